// Round 4
// baseline (103.214 us; speedup 1.0000x reference)
//
#include <hip/hip_runtime.h>
#include <hip/hip_bf16.h>
#include <math.h>

// Problem constants (from reference): B=2048, I=512, O=512
#define B_DIM 2048
#define I_DIM 512
#define O_DIM 512

constexpr int R_ROWS  = 8;               // b-rows per block
constexpr int W_CHUNK = 4;               // i-chunks (threadIdx.y)
constexpr int CHUNK   = I_DIM / W_CHUNK; // 128 i per chunk
constexpr int KP      = CHUNK / 2;       // 64 i-pair rows per chunk
constexpr int KROWS   = I_DIM / 2;       // 256 total i-pair rows
constexpr int QUADS   = I_DIM / 4;       // 128 i-quads

typedef float v2f __attribute__((ext_vector_type(2)));

// Packed fp32 ops (VOP3P). Default op_sel/op_sel_hi = component-wise.
static __device__ __forceinline__ v2f pk_fma(v2f a, v2f b, v2f c) {
    v2f d;
    asm("v_pk_fma_f32 %0, %1, %2, %3" : "=v"(d) : "v"(a), "v"(b), "v"(c));
    return d;
}
static __device__ __forceinline__ v2f pk_mul(v2f a, v2f b) {
    v2f d;
    asm("v_pk_mul_f32 %0, %1, %2" : "=v"(d) : "v"(a), "v"(b));
    return d;
}

// ---------------------------------------------------------------------------
// Setup kernel (fused): blocks [0,512) precompute the affine ab table,
// blocks [512,1536) re-tile x.
//
// ab:  factor[b,i,o] = a[i,o] + bcoef[i,o]*x[b,i], a = 1-w*s, b = w*(2s-1).
//      Layout: float4 (a0,a1,b0,b1) at ab4[k*O_DIM+o], k = i/2. The (a,a)/
//      (b,b) adjacent pairs feed v_pk_fma_f32 directly.
// xt:  xt[g][q][r][0..3] = x[g*8+r][q*4..q*4+3]  (g = b/8, q = i/4).
//      Per main-loop iteration, one g,q slab = 8 rows x 4 i = 128 B
//      contiguous -> merged s_load_dwordx16 pair instead of 8 s_load_dwordx4.
// ---------------------------------------------------------------------------
__global__ __launch_bounds__(256) void setup_kernel(
    const float* __restrict__ x,
    const float* __restrict__ w_logits,
    const float* __restrict__ s_logits,
    float4* __restrict__ ab4,
    float4* __restrict__ xt4)
{
    const int blk = blockIdx.x;
    if (blk < 512) {
        int t = blk * 256 + threadIdx.x;          // 0 .. 131071
        int o  = t & (O_DIM - 1);
        int k  = t >> 9;                          // i-pair index, 0..255
        int i0 = 2 * k;

        float zw0 = w_logits[(i0 + 0) * O_DIM + o];
        float zs0 = s_logits[(i0 + 0) * O_DIM + o];
        float zw1 = w_logits[(i0 + 1) * O_DIM + o];
        float zs1 = s_logits[(i0 + 1) * O_DIM + o];

        float w0 = 1.0f / (1.0f + expf(-zw0));
        float s0 = 1.0f / (1.0f + expf(-zs0));
        float w1 = 1.0f / (1.0f + expf(-zw1));
        float s1 = 1.0f / (1.0f + expf(-zs1));

        float4 v;
        v.x = fmaf(-w0, s0, 1.0f);        // a0
        v.y = fmaf(-w1, s1, 1.0f);        // a1
        v.z = w0 * (2.0f * s0 - 1.0f);    // b0
        v.w = w1 * (2.0f * s1 - 1.0f);    // b1
        ab4[k * O_DIM + o] = v;
    } else {
        int t  = (blk - 512) * 256 + threadIdx.x; // 0 .. 262143
        int q  = t & (QUADS - 1);                 // i-quad, 0..127
        int b  = t >> 7;                          // 0..2047
        float4 v = ((const float4*)x)[(size_t)b * QUADS + q];
        xt4[((size_t)(b >> 3) * QUADS + q) * R_ROWS + (b & 7)] = v;
    }
}

// ---------------------------------------------------------------------------
// Main product kernel. Block (256, 4): lanes = o (coalesced ab stream),
// threadIdx.y = i-chunk (disjoint ab quarters). Grid (2, 256) = 512 blocks
// -> 2 blocks/CU = 32 waves/CU. Inner math is pure v_pk_fma/v_pk_mul.
// ---------------------------------------------------------------------------
__global__ __launch_bounds__(1024, 8) void fuzzy_main(
    const float* __restrict__ xt,      // retiled x, float4[g][q][r]
    const float4* __restrict__ ab4,
    float* __restrict__ out)
{
    __shared__ float part[W_CHUNK][R_ROWS][256];   // 32 KB

    const int o_l = threadIdx.x;              // 0..255
    const int o   = blockIdx.x * 256 + o_l;
    // Pin y wave-uniform so xt addresses are provably uniform -> scalar loads.
    const int y   = __builtin_amdgcn_readfirstlane((int)threadIdx.y); // 0..3
    const int g   = blockIdx.y;               // b-group (8 rows)
    const int b0  = g * R_ROWS;
    const int kbase = y * KP;                 // this chunk's first ab pair-row

    // This (g, y) chunk's x slab: quads [y*32, y*32+32), 8 rows each.
    const float4* xq = (const float4*)xt
                     + ((size_t)g * QUADS + (size_t)y * (KP / 2)) * R_ROWS;

    v2f acc[R_ROWS];
#pragma unroll
    for (int r = 0; r < R_ROWS; ++r) acc[r] = (v2f){1.0f, 1.0f};

    // Prefetch one iteration (2 float4 = 4 i values) ahead.
    float4 p0 = ab4[(size_t)(kbase + 0) * O_DIM + o];
    float4 p1 = ab4[(size_t)(kbase + 1) * O_DIM + o];

    for (int k = 0; k < KP; k += 2) {         // 32 iterations, 4 i per iter
        float4 c0 = p0;                       // (a0,a1,b0,b1) for i=2k,2k+1
        float4 c1 = p1;                       // for i=2k+2,2k+3
        // Wrap prefetch rows into [0,256): last-iter loads dead but in-bounds.
        int kn = (kbase + k + 2) & (KROWS - 1);
        p0 = ab4[(size_t)(kn + 0) * O_DIM + o];
        p1 = ab4[(size_t)(kn + 1) * O_DIM + o];

        const v2f a01 = (v2f){c0.x, c0.y}, b01 = (v2f){c0.z, c0.w};
        const v2f a23 = (v2f){c1.x, c1.y}, b23 = (v2f){c1.z, c1.w};

        const float4* xrow = xq + (size_t)(k >> 1) * R_ROWS; // 128B slab
#pragma unroll
        for (int r = 0; r < R_ROWS; ++r) {
            // Uniform contiguous addresses -> merged s_load_dwordx16 pair.
            float4 xv = xrow[r];
            v2f x01 = (v2f){xv.x, xv.y};
            v2f x23 = (v2f){xv.z, xv.w};
            v2f f01 = pk_fma(b01, x01, a01);
            v2f f23 = pk_fma(b23, x23, a23);
            acc[r]  = pk_mul(acc[r], pk_mul(f01, f23));
        }
    }

    // Combine the 4 i-chunk partials per (row, o) via LDS, single pass.
#pragma unroll
    for (int r = 0; r < R_ROWS; ++r)
        part[y][r][o_l] = acc[r].x * acc[r].y;
    __syncthreads();
    // 8 rows / 4 y-groups -> 2 rows per thread; stride-1 in o -> coalesced.
#pragma unroll
    for (int rr = 0; rr < 2; ++rr) {
        int r8 = y * 2 + rr;
        float v = part[0][r8][o_l] * part[1][r8][o_l]
                * part[2][r8][o_l] * part[3][r8][o_l];
        out[(size_t)(b0 + r8) * O_DIM + o] = v;
    }
}

extern "C" void kernel_launch(void* const* d_in, const int* in_sizes, int n_in,
                              void* d_out, int out_size, void* d_ws, size_t ws_size,
                              hipStream_t stream) {
    const float* x        = (const float*)d_in[0];   // (B, I) fp32
    const float* w_logits = (const float*)d_in[1];   // (I, O) fp32
    const float* s_logits = (const float*)d_in[2];   // (I, O) fp32
    float* out = (float*)d_out;                      // (B, O) fp32
    float4* ab4 = (float4*)d_ws;                     // 2 MB
    float4* xt4 = (float4*)((char*)d_ws + (size_t)I_DIM * O_DIM * 8); // 4 MB

    // Fused setup: 512 ab-blocks + 1024 x-retile blocks.
    setup_kernel<<<dim3(1536), dim3(256), 0, stream>>>(
        x, w_logits, s_logits, ab4, xt4);

    // Grid (O/256, B/R) = (2, 256) = 512 blocks of (256,4)=1024 threads.
    fuzzy_main<<<dim3(O_DIM / 256, B_DIM / R_ROWS), dim3(256, W_CHUNK), 0, stream>>>(
        (const float*)xt4, ab4, out);
}

// Round 5
// 94.267 us; speedup vs baseline: 1.0949x; 1.0949x over previous
//
#include <hip/hip_runtime.h>
#include <hip/hip_bf16.h>
#include <math.h>

// Problem constants (from reference): B=2048, I=512, O=512
#define B_DIM 2048
#define I_DIM 512
#define O_DIM 512

constexpr int R_ROWS  = 8;               // b-rows per block
constexpr int W_CHUNK = 4;               // i-chunks (threadIdx.y)
constexpr int CHUNK   = I_DIM / W_CHUNK; // 128 i per chunk
constexpr int KP      = CHUNK / 2;       // 64 i-pair rows per chunk
constexpr int QUADS   = I_DIM / 4;       // 128 i-quads

// ws layout: xt first, ab4 second, so the benign pipeline overreads
// (x: +128B past xt -> lands in ab4; ab: +32KB past ab4 -> lands in the
// 256MB ws slack) stay inside mapped workspace.
#define XT_BYTES  ((size_t)B_DIM * I_DIM * 4)          // 4 MB
#define AB_OFFSET XT_BYTES

// ---------------------------------------------------------------------------
// Setup kernel (fused): blocks [0,512) precompute the affine ab table,
// blocks [512,1536) re-tile x.
//   factor[b,i,o] = 1 - w*(1 - xnor) = a[i,o] + bcoef[i,o]*x[b,i]
//   a = 1 - w*s ; bcoef = w*(2s - 1)
// ab layout: float4 (a0,a1,b0,b1) at ab4[k*O_DIM+o], k = i/2.
// xt layout: xt[g][q][r] (float4) = x[g*8+r][4q..4q+3]; one (g,q) slab is
// 8 rows x 16B = 128 B contiguous -> two merged s_load_dwordx16 per stage.
// ---------------------------------------------------------------------------
__global__ __launch_bounds__(256) void setup_kernel(
    const float* __restrict__ x,
    const float* __restrict__ w_logits,
    const float* __restrict__ s_logits,
    float4* __restrict__ ab4,
    float4* __restrict__ xt4)
{
    const int blk = blockIdx.x;
    if (blk < 512) {
        int t = blk * 256 + threadIdx.x;          // 0 .. 131071
        int o  = t & (O_DIM - 1);
        int k  = t >> 9;                          // i-pair index, 0..255
        int i0 = 2 * k;

        float zw0 = w_logits[(i0 + 0) * O_DIM + o];
        float zs0 = s_logits[(i0 + 0) * O_DIM + o];
        float zw1 = w_logits[(i0 + 1) * O_DIM + o];
        float zs1 = s_logits[(i0 + 1) * O_DIM + o];

        float w0 = 1.0f / (1.0f + expf(-zw0));
        float s0 = 1.0f / (1.0f + expf(-zs0));
        float w1 = 1.0f / (1.0f + expf(-zw1));
        float s1 = 1.0f / (1.0f + expf(-zs1));

        float4 v;
        v.x = fmaf(-w0, s0, 1.0f);        // a0
        v.y = fmaf(-w1, s1, 1.0f);        // a1
        v.z = w0 * (2.0f * s0 - 1.0f);    // b0
        v.w = w1 * (2.0f * s1 - 1.0f);    // b1
        ab4[k * O_DIM + o] = v;
    } else {
        int t  = (blk - 512) * 256 + threadIdx.x; // 0 .. 262143
        int q  = t & (QUADS - 1);                 // i-quad, 0..127
        int b  = t >> 7;                          // 0..2047
        float4 v = ((const float4*)x)[(size_t)b * QUADS + q];
        xt4[((size_t)(b >> 3) * QUADS + q) * R_ROWS + (b & 7)] = v;
    }
}

// ---------------------------------------------------------------------------
// Main product kernel. Block (256,4): lanes = o (coalesced ab stream),
// threadIdx.y = i-chunk. Grid (2,256) = 512 blocks -> 2 blocks/CU, 32
// waves/CU. Inner loop: scalar v_fma_f32 (pk_fma is NOT double-rate on
// gfx950 -- R4 post-mortem), x from SGPR slabs (1 SGPR operand per fma),
// 2-stage unrolled software pipeline with depth-2 prefetch and zero
// register-rotation copies.
// ---------------------------------------------------------------------------
__global__ __launch_bounds__(1024, 8) void fuzzy_main(
    const float4* __restrict__ xt,     // retiled x, float4[g][q][r]
    const float4* __restrict__ ab4,
    float* __restrict__ out)
{
    __shared__ float part[W_CHUNK][R_ROWS][256];   // 32 KB

    const int o_l = threadIdx.x;              // 0..255
    const int o   = blockIdx.x * 256 + o_l;
    // Pin y wave-uniform so xt addresses are provably uniform -> s_load.
    const int y   = __builtin_amdgcn_readfirstlane((int)threadIdx.y); // 0..3
    const int g   = blockIdx.y;               // b-group (8 rows)
    const int b0  = g * R_ROWS;
    const int kbase = y * KP;                 // this chunk's first ab pair-row

    // Lane-varying base + uniform row offset -> saddr-form global loads.
    const float4* ab_o = ab4 + o;
    // This (g,y) chunk's x slabs: quads [y*32, y*32+32).
    const float4* xq = xt + ((size_t)g * QUADS + (size_t)y * (KP / 2)) * R_ROWS;

    // x pipeline: xa = even slabs, xb = odd slabs (SGPR-resident).
    float4 xa[R_ROWS], xb[R_ROWS];
#pragma unroll
    for (int r = 0; r < R_ROWS; ++r) xa[r] = xq[r];
#pragma unroll
    for (int r = 0; r < R_ROWS; ++r) xb[r] = xq[R_ROWS + r];

    // ab pipeline: pA for even stages, pB for odd stages (depth 2).
    float4 pA0 = ab_o[(size_t)(kbase + 0) * O_DIM];
    float4 pA1 = ab_o[(size_t)(kbase + 1) * O_DIM];
    float4 pB0 = ab_o[(size_t)(kbase + 2) * O_DIM];
    float4 pB1 = ab_o[(size_t)(kbase + 3) * O_DIM];

    float acc0[R_ROWS], acc1[R_ROWS];
#pragma unroll
    for (int r = 0; r < R_ROWS; ++r) { acc0[r] = 1.0f; acc1[r] = 1.0f; }

    for (int k = 0; k < KP; k += 4) {         // 16 outer iters, 2 stages each
        // ---- stage A: pair-rows kbase+k, +k+1 (x slab k/2, even) ----
        {
            float4 c0 = pA0, c1 = pA1;
#pragma unroll
            for (int r = 0; r < R_ROWS; ++r) {
                float4 xv = xa[r];            // SGPRs
                float f0 = fmaf(c0.z, xv.x, c0.x);
                float f1 = fmaf(c0.w, xv.y, c0.y);
                float f2 = fmaf(c1.z, xv.z, c1.x);
                float f3 = fmaf(c1.w, xv.w, c1.y);
                acc0[r] *= f0 * f2;
                acc1[r] *= f1 * f3;
            }
            // Prefetch for iteration k+4 (2 stages ahead). Final loads
            // overrun ab4 by <=32KB / xt by 128B -> inside 256MB ws.
            pA0 = ab_o[(size_t)(kbase + k + 4) * O_DIM];
            pA1 = ab_o[(size_t)(kbase + k + 5) * O_DIM];
            const float4* xs = xq + (size_t)(k / 2 + 2) * R_ROWS;
#pragma unroll
            for (int r = 0; r < R_ROWS; ++r) xa[r] = xs[r];
        }
        // ---- stage B: pair-rows kbase+k+2, +k+3 (x slab k/2+1, odd) ----
        {
            float4 c0 = pB0, c1 = pB1;
#pragma unroll
            for (int r = 0; r < R_ROWS; ++r) {
                float4 xv = xb[r];
                float f0 = fmaf(c0.z, xv.x, c0.x);
                float f1 = fmaf(c0.w, xv.y, c0.y);
                float f2 = fmaf(c1.z, xv.z, c1.x);
                float f3 = fmaf(c1.w, xv.w, c1.y);
                acc0[r] *= f0 * f2;
                acc1[r] *= f1 * f3;
            }
            pB0 = ab_o[(size_t)(kbase + k + 6) * O_DIM];
            pB1 = ab_o[(size_t)(kbase + k + 7) * O_DIM];
            const float4* xs = xq + (size_t)(k / 2 + 3) * R_ROWS;
#pragma unroll
            for (int r = 0; r < R_ROWS; ++r) xb[r] = xs[r];
        }
    }

    // Combine the 4 i-chunk partials per (row, o) via LDS, single pass.
#pragma unroll
    for (int r = 0; r < R_ROWS; ++r)
        part[y][r][o_l] = acc0[r] * acc1[r];
    __syncthreads();
    // 8 rows / 4 y-groups -> 2 rows per thread; stride-1 in o -> coalesced.
#pragma unroll
    for (int rr = 0; rr < 2; ++rr) {
        int r8 = y * 2 + rr;
        float v = part[0][r8][o_l] * part[1][r8][o_l]
                * part[2][r8][o_l] * part[3][r8][o_l];
        out[(size_t)(b0 + r8) * O_DIM + o] = v;
    }
}

extern "C" void kernel_launch(void* const* d_in, const int* in_sizes, int n_in,
                              void* d_out, int out_size, void* d_ws, size_t ws_size,
                              hipStream_t stream) {
    const float* x        = (const float*)d_in[0];   // (B, I) fp32
    const float* w_logits = (const float*)d_in[1];   // (I, O) fp32
    const float* s_logits = (const float*)d_in[2];   // (I, O) fp32
    float* out = (float*)d_out;                      // (B, O) fp32
    float4* xt4 = (float4*)d_ws;                             // [0, 4MB)
    float4* ab4 = (float4*)((char*)d_ws + AB_OFFSET);        // [4MB, 6MB)

    // Fused setup: 512 ab-blocks + 1024 x-retile blocks.
    setup_kernel<<<dim3(1536), dim3(256), 0, stream>>>(
        x, w_logits, s_logits, ab4, xt4);

    // Grid (O/256, B/R) = (2, 256) = 512 blocks of (256,4)=1024 threads.
    fuzzy_main<<<dim3(O_DIM / 256, B_DIM / R_ROWS), dim3(256, W_CHUNK), 0, stream>>>(
        xt4, ab4, out);
}